// Round 1
// baseline (576.563 us; speedup 1.0000x reference)
//
#include <hip/hip_runtime.h>
#include <hip/hip_bf16.h>
#include <cstdint>
#include <cstddef>

#define D_IN  4096
#define D_OUT 4096
#define M_TOK 8192   // 4 * 2048
#define QG    128

typedef __bf16 bf16x8 __attribute__((ext_vector_type(8)));
typedef float  floatx4 __attribute__((ext_vector_type(4)));

// ---------------- scale precompute ----------------
__global__ __launch_bounds__(256) void scale_kernel(const float* __restrict__ ls,
                                                    float* __restrict__ scale) {
    int i = blockIdx.x * 256 + threadIdx.x;
    if (i < D_IN) {
        float s = expf(ls[i]);
        s = fminf(fmaxf(s, 1e-4f), 1e4f);
        scale[i] = s;
    }
}

// ---------------- activation fake-quant (per-row symmetric 8-bit) ----------------
__global__ __launch_bounds__(256) void act_quant(const float* __restrict__ x,
                                                 const float* __restrict__ scale,
                                                 __hip_bfloat16* __restrict__ xq) {
    const int row = blockIdx.x;
    const int tid = threadIdx.x;
    const float* xr = x + (size_t)row * D_IN;

    float v[16];
    float amax = 0.f;
#pragma unroll
    for (int i = 0; i < 16; ++i) {
        int d = tid + i * 256;
        float q = xr[d] / scale[d];   // true fp32 divide to match reference
        v[i] = q;
        amax = fmaxf(amax, fabsf(q));
    }
    // wave64 butterfly reduce
#pragma unroll
    for (int off = 32; off > 0; off >>= 1)
        amax = fmaxf(amax, __shfl_xor(amax, off, 64));
    __shared__ float smax[4];
    if ((tid & 63) == 0) smax[tid >> 6] = amax;
    __syncthreads();
    float m = fmaxf(fmaxf(smax[0], smax[1]), fmaxf(smax[2], smax[3]));
    m = fmaxf(m, 1e-5f);
    const float s = m / 127.0f;

    __hip_bfloat16* xo = xq + (size_t)row * D_IN;
#pragma unroll
    for (int i = 0; i < 16; ++i) {
        int d = tid + i * 256;
        float dq = fminf(fmaxf(rintf(v[i] / s), -128.f), 127.f) * s;
        xo[d] = __float2bfloat16(dq);
    }
}

// ---------------- weight fake-quant (per-128-group asymmetric 4-bit) ----------------
__global__ __launch_bounds__(256) void w_quant(const float* __restrict__ wgt,
                                               const float* __restrict__ scale,
                                               __hip_bfloat16* __restrict__ wq) {
    // one wave per group of 128; 4 waves per block
    const int gid  = blockIdx.x * 4 + (threadIdx.x >> 6);
    const int lane = threadIdx.x & 63;
    const size_t e0 = (size_t)gid * QG + lane * 2;
    const int d0 = (int)(e0 & (D_IN - 1));   // column index (groups never cross rows)

    float2 wv = *(const float2*)(wgt + e0);
    float w0 = wv.x * scale[d0];
    float w1 = wv.y * scale[d0 + 1];

    float mx = fmaxf(w0, w1), mn = fminf(w0, w1);
#pragma unroll
    for (int off = 32; off > 0; off >>= 1) {
        mx = fmaxf(mx, __shfl_xor(mx, off, 64));
        mn = fminf(mn, __shfl_xor(mn, off, 64));
    }
    const float s = fmaxf(mx - mn, 1e-5f) / 15.0f;
    const float z = fminf(fmaxf(-rintf(mn / s), 0.f), 15.f);

    float dq0 = (fminf(fmaxf(rintf(w0 / s) + z, 0.f), 15.f) - z) * s;
    float dq1 = (fminf(fmaxf(rintf(w1 / s) + z, 0.f), 15.f) - z) * s;

    __hip_bfloat162 h;
    h.x = __float2bfloat16(dq0);
    h.y = __float2bfloat16(dq1);
    *(__hip_bfloat162*)(wq + e0) = h;
}

// ---------------- GEMM: C[M,N] = A[M,K] * B[N,K]^T + bias ----------------
// m97-style: 128x128 tile, BK=32, 4 waves (2x2), each wave 4x4 of 16x16x32 bf16 MFMA,
// global_load_lds width=16 staging (no LDS padding -- required by the DMA lane layout).
__global__ __launch_bounds__(256) void gemm_bt(const __hip_bfloat16* __restrict__ A,
                                               const __hip_bfloat16* __restrict__ B,
                                               const float* __restrict__ bias,
                                               float* __restrict__ C) {
    constexpr int K = D_IN;
    __shared__ unsigned short Alds[128 * 32];
    __shared__ unsigned short Blds[128 * 32];

    const int tid  = threadIdx.x;
    const int lane = tid & 63;
    const int w    = tid >> 6;
    const int bn   = blockIdx.x;
    const int bm   = blockIdx.y;
    const int wm   = (w >> 1) * 64;
    const int wn   = (w & 1) * 64;
    const int q    = lane >> 4;   // 0..3 (k-quad)
    const int l16  = lane & 15;

    floatx4 acc[4][4] = {};

    for (int k0 = 0; k0 < K; k0 += 32) {
        __syncthreads();
#pragma unroll
        for (int t = 0; t < 2; ++t) {
            int f = t * 256 + tid;      // 16B chunk id; row = f/4, col8 = f%4
            int r = f >> 2, c = f & 3;
            const __hip_bfloat16* ga = A + (size_t)(bm * 128 + r) * K + k0 + c * 8;
            __builtin_amdgcn_global_load_lds(
                (const __attribute__((address_space(1))) void*)ga,
                (__attribute__((address_space(3))) void*)(Alds + f * 8), 16, 0, 0);
            const __hip_bfloat16* gb = B + (size_t)(bn * 128 + r) * K + k0 + c * 8;
            __builtin_amdgcn_global_load_lds(
                (const __attribute__((address_space(1))) void*)gb,
                (__attribute__((address_space(3))) void*)(Blds + f * 8), 16, 0, 0);
        }
        __syncthreads();

        bf16x8 af[4], bfr[4];
#pragma unroll
        for (int i = 0; i < 4; ++i) {
            af[i]  = *(const bf16x8*)(Alds + (wm + i * 16 + l16) * 32 + q * 8);
            bfr[i] = *(const bf16x8*)(Blds + (wn + i * 16 + l16) * 32 + q * 8);
        }
#pragma unroll
        for (int mi = 0; mi < 4; ++mi)
#pragma unroll
            for (int ni = 0; ni < 4; ++ni)
                acc[mi][ni] = __builtin_amdgcn_mfma_f32_16x16x32_bf16(
                    af[mi], bfr[ni], acc[mi][ni], 0, 0, 0);
    }

    float bv[4];
#pragma unroll
    for (int ni = 0; ni < 4; ++ni)
        bv[ni] = bias[bn * 128 + wn + ni * 16 + l16];

#pragma unroll
    for (int mi = 0; mi < 4; ++mi) {
        int gm = bm * 128 + wm + mi * 16 + q * 4;   // C row = quad*4 + reg
#pragma unroll
        for (int ni = 0; ni < 4; ++ni) {
            int gn = bn * 128 + wn + ni * 16 + l16; // C col = lane&15
            float* cp = C + (size_t)gm * D_OUT + gn;
#pragma unroll
            for (int r = 0; r < 4; ++r)
                cp[(size_t)r * D_OUT] = acc[mi][ni][r] + bv[ni];
        }
    }
}

extern "C" void kernel_launch(void* const* d_in, const int* in_sizes, int n_in,
                              void* d_out, int out_size, void* d_ws, size_t ws_size,
                              hipStream_t stream) {
    const float* x   = (const float*)d_in[0];
    const float* wgt = (const float*)d_in[1];
    const float* bia = (const float*)d_in[2];
    const float* ls  = (const float*)d_in[3];
    float* out = (float*)d_out;

    char* ws = (char*)d_ws;
    float*          scale = (float*)ws;                                  // 16 KB
    __hip_bfloat16* xq    = (__hip_bfloat16*)(ws + (64 << 10));          // 64 MB
    __hip_bfloat16* wq    = (__hip_bfloat16*)(ws + (64 << 10) + ((size_t)64 << 20)); // 32 MB

    scale_kernel<<<(D_IN + 255) / 256, 256, 0, stream>>>(ls, scale);
    act_quant<<<M_TOK, 256, 0, stream>>>(x, scale, xq);
    w_quant<<<(D_OUT * D_IN / QG) / 4, 256, 0, stream>>>(wgt, scale, wq);

    dim3 grid(D_OUT / 128, M_TOK / 128);
    gemm_bt<<<grid, 256, 0, stream>>>(xq, wq, bia, out);
}

// Round 2
// 569.849 us; speedup vs baseline: 1.0118x; 1.0118x over previous
//
#include <hip/hip_runtime.h>
#include <hip/hip_bf16.h>
#include <cstdint>
#include <cstddef>

#define D_IN  4096
#define D_OUT 4096
#define M_TOK 8192   // 4 * 2048
#define QG    128

typedef __bf16 bf16x8 __attribute__((ext_vector_type(8)));
typedef float  floatx4 __attribute__((ext_vector_type(4)));

// ---------------- scale + reciprocal precompute ----------------
__global__ __launch_bounds__(256) void scale_kernel(const float* __restrict__ ls,
                                                    float* __restrict__ scale,
                                                    float* __restrict__ rinv) {
    int i = blockIdx.x * 256 + threadIdx.x;
    if (i < D_IN) {
        float s = expf(ls[i]);
        s = fminf(fmaxf(s, 1e-4f), 1e4f);
        scale[i] = s;
        rinv[i]  = 1.0f / s;   // correctly-rounded divide, <=1 ulp vs x/s
    }
}

// ---------------- activation fake-quant (per-row symmetric 8-bit) ----------------
// one row (4096) per block; float4 loads, ushort4 (4x bf16) stores
__global__ __launch_bounds__(256) void act_quant(const float* __restrict__ x,
                                                 const float* __restrict__ rinv,
                                                 __hip_bfloat16* __restrict__ xq) {
    const int row = blockIdx.x;
    const int tid = threadIdx.x;
    const float4* xr = (const float4*)(x + (size_t)row * D_IN);
    const float4* rv = (const float4*)rinv;

    float v[16];
    float amax = 0.f;
#pragma unroll
    for (int j = 0; j < 4; ++j) {
        int idx = j * 256 + tid;
        float4 xv = xr[idx];
        float4 ri = rv[idx];
        float a = xv.x * ri.x, b = xv.y * ri.y, c = xv.z * ri.z, d = xv.w * ri.w;
        v[j * 4 + 0] = a; v[j * 4 + 1] = b; v[j * 4 + 2] = c; v[j * 4 + 3] = d;
        amax = fmaxf(amax, fmaxf(fmaxf(fabsf(a), fabsf(b)), fmaxf(fabsf(c), fabsf(d))));
    }
#pragma unroll
    for (int off = 32; off > 0; off >>= 1)
        amax = fmaxf(amax, __shfl_xor(amax, off, 64));
    __shared__ float smax[4];
    if ((tid & 63) == 0) smax[tid >> 6] = amax;
    __syncthreads();
    float m = fmaxf(fmaxf(smax[0], smax[1]), fmaxf(smax[2], smax[3]));
    m = fmaxf(m, 1e-5f);
    const float s  = m / 127.0f;
    const float qs = 1.0f / s;

    ushort4* xo = (ushort4*)(xq + (size_t)row * D_IN);
#pragma unroll
    for (int j = 0; j < 4; ++j) {
        union { ushort4 u; __hip_bfloat16 h[4]; } p;
#pragma unroll
        for (int k = 0; k < 4; ++k) {
            float dq = fminf(fmaxf(rintf(v[j * 4 + k] * qs), -128.f), 127.f) * s;
            p.h[k] = __float2bfloat16(dq);
        }
        xo[j * 256 + tid] = p.u;
    }
}

// ---------------- weight fake-quant (per-128-group asymmetric 4-bit) ----------------
// 4 elems/lane, 32 lanes per group => 2 groups per wave, 8 groups per block
__global__ __launch_bounds__(256) void w_quant(const float* __restrict__ wgt,
                                               const float* __restrict__ scale,
                                               __hip_bfloat16* __restrict__ wq) {
    const int wid  = blockIdx.x * 4 + (threadIdx.x >> 6);
    const int lane = threadIdx.x & 63;
    const size_t e0 = (size_t)wid * 256 + lane * 4;
    const int d0 = (int)(e0 & (D_IN - 1));   // column index (groups never cross rows)

    float4 wv = *(const float4*)(wgt + e0);
    float4 sv = *(const float4*)(scale + d0);
    float w0 = wv.x * sv.x, w1 = wv.y * sv.y, w2 = wv.z * sv.z, w3 = wv.w * sv.w;

    float mx = fmaxf(fmaxf(w0, w1), fmaxf(w2, w3));
    float mn = fminf(fminf(w0, w1), fminf(w2, w3));
#pragma unroll
    for (int off = 16; off > 0; off >>= 1) {   // 32-lane group reduce
        mx = fmaxf(mx, __shfl_xor(mx, off, 64));
        mn = fminf(mn, __shfl_xor(mn, off, 64));
    }
    const float s  = fmaxf(mx - mn, 1e-5f) / 15.0f;
    const float rs = 1.0f / s;
    const float z  = fminf(fmaxf(-rintf(mn * rs), 0.f), 15.f);

    union { ushort4 u; __hip_bfloat16 h[4]; } p;
    float wl[4] = {w0, w1, w2, w3};
#pragma unroll
    for (int k = 0; k < 4; ++k) {
        float dq = (fminf(fmaxf(rintf(wl[k] * rs) + z, 0.f), 15.f) - z) * s;
        p.h[k] = __float2bfloat16(dq);
    }
    *(ushort4*)(wq + e0) = p.u;
}

// ---------------- GEMM: C[M,N] = A[M,K] * B[N,K]^T + bias ----------------
// m97-style 128x128 tile, BK=32, 4 waves (2x2), 4x4 of 16x16x32 bf16 MFMA.
// LDS chunk index XOR-swizzled by (row>>1)&3 on BOTH stage and read sides:
// s%8 = (row&1)*4 + (q ^ ((row>>1)&3)) covers all 8 bank groups 2x over the
// 16-lane ds_read phase -> 2-way alias only (free per m136).
__global__ __launch_bounds__(256) void gemm_bt(const __hip_bfloat16* __restrict__ A,
                                               const __hip_bfloat16* __restrict__ B,
                                               const float* __restrict__ bias,
                                               float* __restrict__ C) {
    constexpr int K = D_IN;
    __shared__ unsigned short Alds[128 * 32];
    __shared__ unsigned short Blds[128 * 32];

    const int tid  = threadIdx.x;
    const int lane = tid & 63;
    const int w    = tid >> 6;
    const int bn   = blockIdx.x;
    const int bm   = blockIdx.y;
    const int wm   = (w >> 1) * 64;
    const int wn   = (w & 1) * 64;
    const int q    = lane >> 4;   // 0..3 (k-quad)
    const int l16  = lane & 15;
    const int sw   = (l16 >> 1) & 3;          // read-side swizzle (lane-constant)
    const int colOff = ((q ^ sw)) * 8;        // shorts

    floatx4 acc[4][4] = {};

    for (int k0 = 0; k0 < K; k0 += 32) {
        __syncthreads();
#pragma unroll
        for (int t = 0; t < 2; ++t) {
            int f = t * 256 + tid;            // LDS slot (16B chunks)
            int r = f >> 2;
            int c = (f & 3) ^ ((f >> 3) & 3); // staging-side swizzle
            const __hip_bfloat16* ga = A + (size_t)(bm * 128 + r) * K + k0 + c * 8;
            __builtin_amdgcn_global_load_lds(
                (const __attribute__((address_space(1))) void*)ga,
                (__attribute__((address_space(3))) void*)(Alds + f * 8), 16, 0, 0);
            const __hip_bfloat16* gb = B + (size_t)(bn * 128 + r) * K + k0 + c * 8;
            __builtin_amdgcn_global_load_lds(
                (const __attribute__((address_space(1))) void*)gb,
                (__attribute__((address_space(3))) void*)(Blds + f * 8), 16, 0, 0);
        }
        __syncthreads();

        bf16x8 af[4], bfr[4];
#pragma unroll
        for (int i = 0; i < 4; ++i) {
            af[i]  = *(const bf16x8*)(Alds + (wm + i * 16 + l16) * 32 + colOff);
            bfr[i] = *(const bf16x8*)(Blds + (wn + i * 16 + l16) * 32 + colOff);
        }
#pragma unroll
        for (int mi = 0; mi < 4; ++mi)
#pragma unroll
            for (int ni = 0; ni < 4; ++ni)
                acc[mi][ni] = __builtin_amdgcn_mfma_f32_16x16x32_bf16(
                    af[mi], bfr[ni], acc[mi][ni], 0, 0, 0);
    }

    float bv[4];
#pragma unroll
    for (int ni = 0; ni < 4; ++ni)
        bv[ni] = bias[bn * 128 + wn + ni * 16 + l16];

#pragma unroll
    for (int mi = 0; mi < 4; ++mi) {
        int gm = bm * 128 + wm + mi * 16 + q * 4;   // C row = quad*4 + reg
#pragma unroll
        for (int ni = 0; ni < 4; ++ni) {
            int gn = bn * 128 + wn + ni * 16 + l16; // C col = lane&15
            float* cp = C + (size_t)gm * D_OUT + gn;
#pragma unroll
            for (int r = 0; r < 4; ++r)
                cp[(size_t)r * D_OUT] = acc[mi][ni][r] + bv[ni];
        }
    }
}

extern "C" void kernel_launch(void* const* d_in, const int* in_sizes, int n_in,
                              void* d_out, int out_size, void* d_ws, size_t ws_size,
                              hipStream_t stream) {
    const float* x   = (const float*)d_in[0];
    const float* wgt = (const float*)d_in[1];
    const float* bia = (const float*)d_in[2];
    const float* ls  = (const float*)d_in[3];
    float* out = (float*)d_out;

    char* ws = (char*)d_ws;
    float*          scale = (float*)ws;                                   // 16 KB
    float*          rinv  = (float*)(ws + (16 << 10));                    // 16 KB
    __hip_bfloat16* xq    = (__hip_bfloat16*)(ws + (64 << 10));           // 64 MB
    __hip_bfloat16* wq    = (__hip_bfloat16*)(ws + (64 << 10) + ((size_t)64 << 20)); // 32 MB

    scale_kernel<<<(D_IN + 255) / 256, 256, 0, stream>>>(ls, scale, rinv);
    act_quant<<<M_TOK, 256, 0, stream>>>(x, rinv, xq);
    w_quant<<<(D_OUT * D_IN / 256) / 4, 256, 0, stream>>>(wgt, scale, wq);

    dim3 grid(D_OUT / 128, M_TOK / 128);
    gemm_bt<<<grid, 256, 0, stream>>>(xq, wq, bia, out);
}